// Round 17
// baseline (200.230 us; speedup 1.0000x reference)
//
#include <hip/hip_runtime.h>
#include <hip/hip_bf16.h>
#include <cstdint>
#include <cstddef>

#define B_ 8
#define N_ 4096
#define DIM_ 768
#define H_ 12
#define M_ (B_*N_)        // 32768
#define SCALE_ 0.125f
#define KDIM 768
#define NKT 12
#define NITER 6

typedef __attribute__((ext_vector_type(8))) short s8v;
typedef __attribute__((ext_vector_type(4))) float f4v;

__device__ inline float bf2f(unsigned short u) {
    unsigned v = ((unsigned)u) << 16;
    return __builtin_bit_cast(float, v);
}
__device__ inline unsigned short f2bf(float f) {
    unsigned u = __builtin_bit_cast(unsigned, f);
    return (unsigned short)((u + 0x7FFFu + ((u >> 16) & 1u)) >> 16);
}
__device__ inline void gload16(const void* g, void* l) {
    __builtin_amdgcn_global_load_lds(
        (const __attribute__((address_space(1))) void*)g,
        (__attribute__((address_space(3))) void*)l, 16, 0, 0);
}

#define BARX() __builtin_amdgcn_s_barrier()
#define PRIO1() __builtin_amdgcn_s_setprio(1)
#define PRIO0() __builtin_amdgcn_s_setprio(0)
#define VM4() asm volatile("s_waitcnt vmcnt(4)" ::: "memory")
#define VM2() asm volatile("s_waitcnt vmcnt(2)" ::: "memory")
#define VM0() asm volatile("s_waitcnt vmcnt(0)" ::: "memory")

// LDS layout for score_pass (total 64000 B -> 2 blocks/CU):
//   A bufs:  0..16384, 16384..32768   (128 rows x 64 cols bf16 each)
//   V:       32768..57344             (12 kts x 2048)
//   E:       57344..62976             (16 heads x 352 B)
//   Lm:      62976..63488  Ls: 63488..64000
#define EOFF 57344
#define LMOFF 62976
#define LSOFF 63488

// ---------------- score_pass: per (b, 128-row slice): scores = x @ V^T (MFMA),
// block softmax, P = E^T X (MFMA, LDS-restaged x).  Grid: 256 blocks, 2/CU.
// PATH 0: V = avec [16][768] shared.  PATH 1: V = bvecs [B][16][768] per batch.
// Emits pv[(b*32+slice)*12+h][768] and pms[bh][slice]{m,s}.
template<int PATH>
__global__ __launch_bounds__(512, 2)
void score_pass(const unsigned short* __restrict__ xb,
                const unsigned short* __restrict__ Vmat,
                float* __restrict__ pv, float* __restrict__ pms)
{
    __shared__ __align__(16) char smem[64000];
    const int tid = threadIdx.x;
    const int l = tid & 63, w = tid >> 6;
    const int lr = l & 15, g = l >> 4;

    const int nwg = gridDim.x, cpx = nwg >> 3;
    const int bid = blockIdx.x;
    const int tm = (bid & 7) * cpx + (bid >> 3);
    const int m0 = tm * 128;
    const int b = m0 >> 12;
    const int slice = (m0 & (N_ - 1)) >> 7;      // 0..31

    const long ldaB = (long)KDIM * 2;
    const int srA = w * 8 + (l >> 3);
    const int kbs = (l & 7) * 16;
    const int kbx = kbs ^ ((srA & 7) << 4);
    long offA[2];
    offA[0] = (long)(srA) * ldaB + kbx;          // rows 0-63
    offA[1] = (long)(64 + srA) * ldaB + kbx;     // rows 64-127

    const char* Abase = (const char*)(xb + (size_t)m0 * KDIM);
    const char* Vbase = (const char*)Vmat + (PATH ? (size_t)b * 16 * KDIM * 2 : 0);

    const int kx0 = (g * 16) ^ ((lr & 7) << 4);
    const int kx1 = (64 + g * 16) ^ ((lr & 7) << 4);

#define STG_A(buf_, kt_) { \
    const char* s0_ = Abase + (long)(kt_) * 2; \
    char* d0_ = smem + (buf_) * 16384 + w * 1024; \
    gload16(s0_ + offA[0], d0_); \
    gload16(s0_ + offA[1], d0_ + 8192); }

    // stage V (waves 0,1; pre-swizzled source, linear dst)
    if (w < 2) {
        const int rw = l >> 3;
        const int by = ((l & 7) * 16) ^ (rw << 4);
#pragma unroll
        for (int k6 = 0; k6 < 6; ++k6) {
            const int kt = w * 6 + k6;
            gload16(Vbase + (size_t)rw * 1536 + kt * 128 + by,
                    smem + 32768 + kt * 2048);
            gload16(Vbase + (size_t)(8 + rw) * 1536 + kt * 128 + by,
                    smem + 32768 + kt * 2048 + 1024);
        }
    }
    STG_A(0, 0); STG_A(1, 64);
    VM2(); BARX();

    // phase 1: scores = x @ V^T  (wave w owns rows w*16..+15)
    f4v sacc = {};
    const int hi1 = w >> 2, loc1 = (w & 3) * 16;
    for (int kt = 0; kt < 12; ++kt) {
        const int buf = kt & 1;
        {
            const char* ab = smem + buf * 16384 + hi1 * 8192 + (loc1 + lr) * 128;
            s8v a0 = *(const s8v*)(ab + kx0);
            s8v a1 = *(const s8v*)(ab + kx1);
            const char* vb = smem + 32768 + kt * 2048 + lr * 128;
            s8v b0 = *(const s8v*)(vb + kx0);
            s8v b1 = *(const s8v*)(vb + kx1);
            sacc = __builtin_amdgcn_mfma_f32_16x16x32_bf16(a0, b0, sacc, 0, 0, 0);
            sacc = __builtin_amdgcn_mfma_f32_16x16x32_bf16(a1, b1, sacc, 0, 0, 0);
        }
        BARX();
        if (kt + 2 < 12) STG_A(buf, (kt + 2) * 64);
        if (kt <= 9) { VM2(); } else { VM0(); }
        BARX();
    }

    float dd[4];
#pragma unroll
    for (int r = 0; r < 4; ++r) dd[r] = sacc[r] * SCALE_;

    float mw = fmaxf(fmaxf(dd[0], dd[1]), fmaxf(dd[2], dd[3]));
    mw = fmaxf(mw, __shfl_xor(mw, 16));
    mw = fmaxf(mw, __shfl_xor(mw, 32));
    float* Lm = (float*)(smem + LMOFF);
    float* Ls = (float*)(smem + LSOFF);
    if (l < 16) Lm[w * 16 + lr] = mw;
    __syncthreads();
    float mfin = Lm[lr];
#pragma unroll
    for (int w2 = 1; w2 < 8; ++w2) mfin = fmaxf(mfin, Lm[w2 * 16 + lr]);

    float ss = 0.f;
#pragma unroll
    for (int r = 0; r < 4; ++r) {
        const float e = __expf(dd[r] - mfin);
        ss += e;
        const int row = w * 16 + g * 4 + r;
        *(unsigned short*)(smem + EOFF + lr * 352 + row * 2) = f2bf(e);
    }
    ss += __shfl_xor(ss, 16);
    ss += __shfl_xor(ss, 32);
    if (l < 16) Ls[w * 16 + lr] = ss;
    __syncthreads();

    if (tid < 12) {
        float S = 0.f;
#pragma unroll
        for (int w2 = 0; w2 < 8; ++w2) S += Ls[w2 * 16 + tid];
        float M2 = Lm[tid];
#pragma unroll
        for (int w2 = 1; w2 < 8; ++w2) M2 = fmaxf(M2, Lm[w2 * 16 + tid]);
        pms[((size_t)(b * H_ + tid) * 32 + slice) * 2 + 0] = M2;
        pms[((size_t)(b * H_ + tid) * 32 + slice) * 2 + 1] = S;
    }
    __syncthreads();

    // phase 2: P[h][d] = sum_n E[n][h] x[n][d]  (restage x, MFMA A=E^T B=X)
    for (int it = 0; it < 6; ++it) {
        STG_A(0, (it * 2) * 64);
        STG_A(1, (it * 2 + 1) * 64);
        VM0(); BARX();
        const int buf = w >> 2;
        const int kt = it * 2 + buf;
        const int d0 = (w & 3) * 16;
        const int dby = (d0 + (l & 15)) * 2;
        f4v pacc = {};
#pragma unroll
        for (int c = 0; c < 4; ++c) {
            s8v ae = *(const s8v*)(smem + EOFF + (l & 15) * 352
                                   + (c * 32 + (l >> 4) * 8) * 2);
            const char* xr = smem + buf * 16384 + (c >> 1) * 8192;
            const int nb = (c & 1) * 32 + (l >> 4) * 8;
            s8v bx;
#pragma unroll
            for (int j = 0; j < 8; ++j)
                bx[j] = (short)*(const unsigned short*)(xr + (nb + j) * 128 + (dby ^ (j << 4)));
            pacc = __builtin_amdgcn_mfma_f32_16x16x32_bf16(ae, bx, pacc, 0, 0, 0);
        }
        if ((l >> 4) < 3) {
#pragma unroll
            for (int r = 0; r < 4; ++r) {
                const int h = (l >> 4) * 4 + r;
                pv[((size_t)(b * 32 + slice) * 12 + h) * 768
                   + kt * 64 + d0 + (l & 15)] = pacc[r];
            }
        }
        BARX();
    }
#undef STG_A
}

// ---------------- 128x256 4-phase bf16 GEMM (unchanged, proven) ----------------
// MODE 0: Cf[row,col] = A@B_b^T + bias[col] (f32); B_b per batch (row/4096).
// MODE 1: CbO[row,col] = bf16(A@B^T + addW[(row%768)*768+col]); B shared (wvT).
template<int MODE>
__global__ __launch_bounds__(512, 2)
void gemm128(const unsigned short* __restrict__ A, int ldaE,
             const unsigned short* __restrict__ Bmat,
             float* __restrict__ Cf, unsigned short* __restrict__ CbO,
             const float* __restrict__ bias, const float* __restrict__ addW,
             int Nc, int ntn)
{
    __shared__ __align__(16) char smem[98304];
    const int tid = threadIdx.x;
    const int l = tid & 63, w = tid >> 6;
    const int lr = l & 15, g = l >> 4;
    const int wm = w >> 2, wn = w & 3;

    const int nwg = gridDim.x, cpx = nwg >> 3;
    const int bid = blockIdx.x;
    const int lg = (bid & 7) * cpx + (bid >> 3);
    const int tm = lg / ntn, tn = lg % ntn;
    const int m0 = tm * 128, n0 = tn * 256;

    const long ldaB = (long)ldaE * 2;
    const long ldbB = (long)KDIM * 2;

    const unsigned short* Bp = Bmat;
    if (MODE == 0) Bp = Bmat + (size_t)(m0 >> 12) * (DIM_ * DIM_);

    const int srA = w * 8 + (l >> 3);
    const int kbs = (l & 7) * 16;
    const int kbx = kbs ^ ((srA & 7) << 4);
    long offA[2], offB[2];
    offA[0] = (long)(srA) * ldaB + kbx;
    offA[1] = (long)(64 + srA) * ldaB + kbx;
    offB[0] = (long)(((srA >> 5)) * 64 + (srA & 31)) * ldbB + kbx;
    offB[1] = (long)((2 + (srA >> 5)) * 64 + (srA & 31)) * ldbB + kbx;

    const char* Abase = (const char*)(A + (size_t)m0 * ldaE);
    const char* Bbase = (const char*)(Bp + (size_t)n0 * KDIM);

    const int aoff = (wm * 64 + lr) * 128;
    const int boff = (wn * 32 + lr) * 128;
    const int kx0 = (g * 16) ^ ((lr & 7) << 4);
    const int kx1 = (64 + g * 16) ^ ((lr & 7) << 4);

    f4v acc[4][4] = {};
    s8v af[4][2];
    s8v bfr[2][2][2];

#define STG_A1(buf_, kt_) { \
    const char* s0_ = Abase + (long)(kt_) * 2; \
    char* d0_ = smem + ((buf_) * 3) * 16384 + w * 1024; \
    gload16(s0_ + offA[0], d0_); \
    gload16(s0_ + offA[1], d0_ + 8192); }

#define STG_B1(buf_, qn_, kt_) { \
    const char* s0_ = Bbase + (long)(kt_) * 2 + (long)(qn_) * 32 * ldbB; \
    char* d0_ = smem + ((buf_) * 3 + 1 + (qn_)) * 16384 + w * 1024; \
    gload16(s0_ + offB[0], d0_); \
    gload16(s0_ + offB[1], d0_ + 8192); }

#define DS_A1(buf_) { \
    const char* ba_ = smem + ((buf_) * 3) * 16384 + aoff; \
    af[0][0] = *(const s8v*)(ba_ +    0 + kx0); af[0][1] = *(const s8v*)(ba_ +    0 + kx1); \
    af[1][0] = *(const s8v*)(ba_ + 2048 + kx0); af[1][1] = *(const s8v*)(ba_ + 2048 + kx1); \
    af[2][0] = *(const s8v*)(ba_ + 4096 + kx0); af[2][1] = *(const s8v*)(ba_ + 4096 + kx1); \
    af[3][0] = *(const s8v*)(ba_ + 6144 + kx0); af[3][1] = *(const s8v*)(ba_ + 6144 + kx1); }

#define DS_B1(buf_, qn_) { \
    const char* bb_ = smem + ((buf_) * 3 + 1 + (qn_)) * 16384 + boff; \
    bfr[qn_][0][0] = *(const s8v*)(bb_ +    0 + kx0); bfr[qn_][0][1] = *(const s8v*)(bb_ +    0 + kx1); \
    bfr[qn_][1][0] = *(const s8v*)(bb_ + 2048 + kx0); bfr[qn_][1][1] = *(const s8v*)(bb_ + 2048 + kx1); }

#define MM1(fm_, fng_, qn_, kk_) \
    acc[fm_][fng_] = __builtin_amdgcn_mfma_f32_16x16x32_bf16(af[fm_][kk_], bfr[qn_][(fng_)&1][kk_], acc[fm_][fng_], 0, 0, 0);

#define MFMA16_1(qn_, kk_) \
    MM1(0, (qn_)*2+0, qn_, kk_) MM1(0, (qn_)*2+1, qn_, kk_) \
    MM1(1, (qn_)*2+0, qn_, kk_) MM1(1, (qn_)*2+1, qn_, kk_) \
    MM1(2, (qn_)*2+0, qn_, kk_) MM1(2, (qn_)*2+1, qn_, kk_) \
    MM1(3, (qn_)*2+0, qn_, kk_) MM1(3, (qn_)*2+1, qn_, kk_)

#define MFMA32_1(qn_) { MFMA16_1(qn_, 0) MFMA16_1(qn_, 1) }

    STG_A1(0, 0); STG_B1(0, 0, 0); STG_B1(0, 1, 0);
    STG_A1(1, 64); STG_B1(1, 0, 64);
    VM4(); BARX();

    for (int i = 0; i < NITER; ++i) {
        const int t1k = (2 * i + 1) * 64, t2k = (2 * i + 2) * 64, t3k = (2 * i + 3) * 64;
        const bool h2 = (2 * i + 2) < NKT, h3 = (2 * i + 3) < NKT;
        const bool last = (i == NITER - 1);
        DS_A1(0); DS_B1(0, 0); STG_B1(1, 1, t1k);
        BARX(); PRIO1(); MFMA32_1(0); PRIO0(); BARX();
        DS_B1(0, 1); if (h2) { STG_A1(0, t2k); STG_B1(0, 0, t2k); }
        BARX(); PRIO1(); MFMA32_1(1); PRIO0();
        if (last) { VM0(); } else { VM4(); }
        BARX();
        DS_A1(1); DS_B1(1, 0); if (h2) STG_B1(0, 1, t2k);
        BARX(); PRIO1(); MFMA32_1(0); PRIO0(); BARX();
        DS_B1(1, 1); if (h3) { STG_A1(1, t3k); STG_B1(1, 0, t3k); }
        BARX(); PRIO1(); MFMA32_1(1); PRIO0();
        if (last) { VM0(); } else { VM4(); }
        BARX();
    }

    const int jb = m0 % DIM_;   // row offset within batch (MODE 1)
#pragma unroll
    for (int fm = 0; fm < 4; ++fm) {
#pragma unroll
        for (int fng = 0; fng < 4; ++fng) {
            const int col = n0 + wn * 64 + fng * 16 + lr;
#pragma unroll
            for (int r = 0; r < 4; ++r) {
                const int ro = wm * 64 + fm * 16 + g * 4 + r;
                const int row = m0 + ro;
                if (MODE == 0) {
                    Cf[(size_t)row * Nc + col] = acc[fm][fng][r] + bias[col];
                } else {
                    CbO[(size_t)row * Nc + col] =
                        f2bf(acc[fm][fng][r] + addW[(size_t)(jb + ro) * DIM_ + col]);
                }
            }
        }
    }
#undef STG_A1
#undef STG_B1
#undef DS_A1
#undef DS_B1
#undef MM1
#undef MFMA16_1
#undef MFMA32_1
}

// ---------------- reduce_a: alpha partials -> bvecs = Wk_h^T(gq*wk)  (bf16) ----------
__global__ __launch_bounds__(256)
void reduce_a(const float* __restrict__ pv1, const float* __restrict__ pms1,
              const float* __restrict__ Wqkv, const float* __restrict__ w_k,
              unsigned short* __restrict__ bvecs)
{
    const int b = blockIdx.x / H_, h = blockIdx.x % H_;
    const int t = threadIdx.x;
    const int w = t >> 6, l = t & 63;
    __shared__ float Svec[768];
    __shared__ float ew[32];
    __shared__ float Ssh;
    __shared__ float gqwk[64];

    const float* pp = pms1 + (size_t)(b * H_ + h) * 32 * 2;
    float M = pp[0];
    for (int s = 1; s < 32; ++s) M = fmaxf(M, pp[s * 2]);
    if (t < 32) ew[t] = __expf(pp[t * 2] - M);
    __syncthreads();
    if (t == 0) {
        float S = 0.f;
        for (int s = 0; s < 32; ++s) S += ew[s] * pp[s * 2 + 1];
        Ssh = S;
    }
#pragma unroll
    for (int j = 0; j < 3; ++j) {
        const int col = t + j * 256;
        float v = 0.f;
        for (int s = 0; s < 32; ++s)
            v += ew[s] * pv1[((size_t)(b * 32 + s) * 12 + h) * 768 + col];
        Svec[col] = v;
    }
    __syncthreads();

    // gq matvec (Wq rows, coalesced): wave w outputs w*16..+15
    const float invS = 1.f / Ssh;
    for (int i = 0; i < 16; ++i) {
        const int o = w * 16 + i;
        const float* wr = Wqkv + (size_t)(h * 64 + o) * 768;
        float s = 0.f;
#pragma unroll
        for (int j = 0; j < 12; ++j)
            s += wr[l + j * 64] * Svec[l + j * 64];
        s += __shfl_xor(s, 1); s += __shfl_xor(s, 2); s += __shfl_xor(s, 4);
        s += __shfl_xor(s, 8); s += __shfl_xor(s, 16); s += __shfl_xor(s, 32);
        if (l == 0) gqwk[o] = (s * invS) * w_k[h * 64 + o];
    }
    __syncthreads();

    // bvec[d] = sum_c gqwk[c] * Wk[h*64+c][d]   (coalesced over d)
#pragma unroll
    for (int j = 0; j < 3; ++j) {
        const int dcol = t + j * 256;
        float bv = 0.f;
        for (int c = 0; c < 64; ++c)
            bv += gqwk[c] * Wqkv[(size_t)(DIM_ + h * 64 + c) * 768 + dcol];
        bvecs[(size_t)(b * 16 + h) * 768 + dcol] = f2bf(bv);
        if (h < 4) bvecs[(size_t)(b * 16 + 12 + h) * 768 + dcol] = 0;
    }
}

// ---------------- reduce_b: beta partials -> gkv[b*768 + h*64 + o] ----------
__global__ __launch_bounds__(256)
void reduce_b(const float* __restrict__ pv2, const float* __restrict__ pms2,
              const float* __restrict__ Wqkv, float* __restrict__ gkv)
{
    const int b = blockIdx.x / H_, h = blockIdx.x % H_;
    const int t = threadIdx.x;
    const int w = t >> 6, l = t & 63;
    __shared__ float Svec[768];
    __shared__ float ew[32];
    __shared__ float Ssh;

    const float* pp = pms2 + (size_t)(b * H_ + h) * 32 * 2;
    float M = pp[0];
    for (int s = 1; s < 32; ++s) M = fmaxf(M, pp[s * 2]);
    if (t < 32) ew[t] = __expf(pp[t * 2] - M);
    __syncthreads();
    if (t == 0) {
        float S = 0.f;
        for (int s = 0; s < 32; ++s) S += ew[s] * pp[s * 2 + 1];
        Ssh = S;
    }
#pragma unroll
    for (int j = 0; j < 3; ++j) {
        const int col = t + j * 256;
        float v = 0.f;
        for (int s = 0; s < 32; ++s)
            v += ew[s] * pv2[((size_t)(b * 32 + s) * 12 + h) * 768 + col];
        Svec[col] = v;
    }
    __syncthreads();

    // gk matvec (Wk rows, coalesced)
    const float invS = 1.f / Ssh;
    for (int i = 0; i < 16; ++i) {
        const int o = w * 16 + i;
        const float* wr = Wqkv + (size_t)(DIM_ + h * 64 + o) * 768;
        float s = 0.f;
#pragma unroll
        for (int j = 0; j < 12; ++j)
            s += wr[l + j * 64] * Svec[l + j * 64];
        s += __shfl_xor(s, 1); s += __shfl_xor(s, 2); s += __shfl_xor(s, 4);
        s += __shfl_xor(s, 8); s += __shfl_xor(s, 16); s += __shfl_xor(s, 32);
        if (l == 0) gkv[(size_t)b * DIM_ + h * 64 + o] = s * invS;
    }
}

// ---------------- conversion (x -> xb, Wv -> wvT) + fused avec_prep ----------
// Blocks [0, nblk_cvt): cvt work.  Blocks [nblk_cvt, nblk_cvt+16): avec rows.
__global__ void cvt_all(const float* __restrict__ x, const float* __restrict__ Wqkv,
                        const float* __restrict__ w_q,
                        unsigned short* __restrict__ xb, unsigned short* __restrict__ wvT,
                        unsigned short* __restrict__ avecb,
                        int n4x, int nblk_cvt)
{
    if ((int)blockIdx.x >= nblk_cvt) {
        const int h = blockIdx.x - nblk_cvt;     // 0..15
        const int t = threadIdx.x;
        if (h >= H_) {
#pragma unroll
            for (int j = 0; j < 3; ++j) avecb[(size_t)h * 768 + t + j * 256] = 0;
            return;
        }
        __shared__ float wl[64];
        if (t < 64) wl[t] = w_q[h * 64 + t];
        __syncthreads();
#pragma unroll
        for (int j = 0; j < 3; ++j) {
            const int dcol = t + j * 256;
            float a = 0.f;
            for (int c = 0; c < 64; ++c)
                a += wl[c] * Wqkv[(size_t)(h * 64 + c) * 768 + dcol];
            avecb[(size_t)h * 768 + dcol] = f2bf(a);
        }
        return;
    }
    int i = blockIdx.x * 256 + threadIdx.x;
    if (i < n4x) {
        float4 v = ((const float4*)x)[i];
        ushort4 o;
        o.x = f2bf(v.x); o.y = f2bf(v.y); o.z = f2bf(v.z); o.w = f2bf(v.w);
        ((ushort4*)xb)[i] = o;
    } else {
        const int k = i - n4x;
        const int ii = k % DIM_;
        const int c0 = (k / DIM_) * 4;
        ushort4 o;
        o.x = f2bf(Wqkv[(size_t)(2 * DIM_ + c0 + 0) * DIM_ + ii]);
        o.y = f2bf(Wqkv[(size_t)(2 * DIM_ + c0 + 1) * DIM_ + ii]);
        o.z = f2bf(Wqkv[(size_t)(2 * DIM_ + c0 + 2) * DIM_ + ii]);
        o.w = f2bf(Wqkv[(size_t)(2 * DIM_ + c0 + 3) * DIM_ + ii]);
        *(ushort4*)&wvT[(size_t)ii * DIM_ + c0] = o;
    }
}

// ---------------- fold gk into Wp: W2[b][j][c] = bf16(Wp[j][c] * gk[b*768+c]) --------
__global__ __launch_bounds__(256)
void fold_wp(const float* __restrict__ Wp, const float* __restrict__ gk,
             unsigned short* __restrict__ W2)
{
    int idx = blockIdx.x * 256 + threadIdx.x;
    int e4 = idx * 4;
    int b = (int)((unsigned)e4 / (unsigned)(DIM_ * DIM_));
    int rem = e4 - b * (DIM_ * DIM_);
    int c = rem % DIM_;
    float4 wv = *(const float4*)&Wp[rem];
    const float* gp = &gk[b * DIM_ + c];
    ushort4 o;
    o.x = f2bf(wv.x * gp[0]); o.y = f2bf(wv.y * gp[1]);
    o.z = f2bf(wv.z * gp[2]); o.w = f2bf(wv.w * gp[3]);
    *(ushort4*)&W2[e4] = o;
}

extern "C" void kernel_launch(void* const* d_in, const int* in_sizes, int n_in,
                              void* d_out, int out_size, void* d_ws, size_t ws_size,
                              hipStream_t stream)
{
    const float* x    = (const float*)d_in[0];
    const float* Wqkv = (const float*)d_in[1];
    const float* Wp   = (const float*)d_in[2];
    const float* bp   = (const float*)d_in[3];
    const float* w_q  = (const float*)d_in[4];
    const float* w_k  = (const float*)d_in[5];
    float* out = (float*)d_out;

    constexpr size_t NXB = (size_t)M_ * DIM_;
    constexpr size_t NWV = (size_t)DIM_ * DIM_;
    constexpr size_t NW2 = (size_t)B_ * DIM_ * DIM_;

    char* p = (char*)d_ws;
    unsigned short* xb    = (unsigned short*)p; p += NXB * 2;
    unsigned short* wvT   = (unsigned short*)p; p += NWV * 2;
    unsigned short* w2b   = (unsigned short*)p; p += NW2 * 2;
    unsigned short* w4b   = (unsigned short*)p; p += NW2 * 2;
    unsigned short* avecb = (unsigned short*)p; p += (size_t)16 * 768 * 2;
    unsigned short* bvecs = (unsigned short*)p; p += (size_t)B_ * 16 * 768 * 2;
    float* pv1  = (float*)p; p += (size_t)B_ * 32 * 12 * 768 * 4;
    float* pms1 = (float*)p; p += (size_t)B_ * H_ * 32 * 2 * 4;
    float* pv2  = (float*)p; p += (size_t)B_ * 32 * 12 * 768 * 4;
    float* pms2 = (float*)p; p += (size_t)B_ * H_ * 32 * 2 * 4;
    float* gkv  = (float*)p; p += (size_t)B_ * DIM_ * 4;

    // 1) convert x (bf16) + Wv^T (bf16) + avec (fused, +16 blocks)
    constexpr int N4X  = (int)(NXB / 4);
    constexpr int NBLK = (N4X + (int)(NWV / 4)) / 256;
    cvt_all<<<NBLK + 16, 256, 0, stream>>>(x, Wqkv, w_q, xb, wvT, avecb, N4X, NBLK);

    // 2) alpha score pass (256 blocks, 2/CU)
    score_pass<0><<<256, 512, 0, stream>>>(xb, avecb, pv1, pms1);

    // 3) alpha reduce -> bvecs = Wk_h^T(gq*wk)  (bf16 [B][16][768])
    reduce_a<<<B_ * H_, 256, 0, stream>>>(pv1, pms1, Wqkv, w_k, bvecs);

    // 4) beta score pass (256 blocks)
    score_pass<1><<<256, 512, 0, stream>>>(xb, bvecs, pv2, pms2);

    // 5) beta reduce -> gkv = global_k
    reduce_b<<<B_ * H_, 256, 0, stream>>>(pv2, pms2, Wqkv, gkv);

    // 6) W2[b] = Wp * gk_b (bf16)
    fold_wp<<<(int)(NW2 / 4 / 256), 256, 0, stream>>>(Wp, gkv, w2b);

    // 7) W4 = W2 @ Wv + Wq  (flat [6144,768] GEMM, 144 blocks)
    gemm128<1><<<48 * 3, 512, 0, stream>>>(w2b, DIM_, wvT, nullptr, w4b, nullptr, Wqkv,
                                           DIM_, 3);

    // 8) out = x @ W4_b^T + bp   (768 blocks)
    gemm128<0><<<256 * 3, 512, 0, stream>>>(xb, DIM_, w4b, out, nullptr, bp, nullptr,
                                            DIM_, 3);
}

// Round 18
// 195.661 us; speedup vs baseline: 1.0234x; 1.0234x over previous
//
#include <hip/hip_runtime.h>
#include <hip/hip_bf16.h>
#include <cstdint>
#include <cstddef>

#define B_ 8
#define N_ 4096
#define DIM_ 768
#define H_ 12
#define M_ (B_*N_)        // 32768
#define SCALE_ 0.125f
#define KDIM 768
#define NKT 12
#define NITER 6

typedef __attribute__((ext_vector_type(8))) short s8v;
typedef __attribute__((ext_vector_type(4))) float f4v;

__device__ inline float bf2f(unsigned short u) {
    unsigned v = ((unsigned)u) << 16;
    return __builtin_bit_cast(float, v);
}
__device__ inline unsigned short f2bf(float f) {
    unsigned u = __builtin_bit_cast(unsigned, f);
    return (unsigned short)((u + 0x7FFFu + ((u >> 16) & 1u)) >> 16);
}
__device__ inline void gload16(const void* g, void* l) {
    __builtin_amdgcn_global_load_lds(
        (const __attribute__((address_space(1))) void*)g,
        (__attribute__((address_space(3))) void*)l, 16, 0, 0);
}

#define BARX() __builtin_amdgcn_s_barrier()
#define PRIO1() __builtin_amdgcn_s_setprio(1)
#define PRIO0() __builtin_amdgcn_s_setprio(0)
#define VM4() asm volatile("s_waitcnt vmcnt(4)" ::: "memory")
#define VM2() asm volatile("s_waitcnt vmcnt(2)" ::: "memory")
#define VM0() asm volatile("s_waitcnt vmcnt(0)" ::: "memory")

// LDS layout for score_pass (total 64000 B -> 2 blocks/CU):
#define EOFF 57344
#define LMOFF 62976
#define LSOFF 63488

// ---------------- score_pass (unchanged from R17, proven) ----------------
template<int PATH>
__global__ __launch_bounds__(512, 2)
void score_pass(const unsigned short* __restrict__ xb,
                const unsigned short* __restrict__ Vmat,
                float* __restrict__ pv, float* __restrict__ pms)
{
    __shared__ __align__(16) char smem[64000];
    const int tid = threadIdx.x;
    const int l = tid & 63, w = tid >> 6;
    const int lr = l & 15, g = l >> 4;

    const int nwg = gridDim.x, cpx = nwg >> 3;
    const int bid = blockIdx.x;
    const int tm = (bid & 7) * cpx + (bid >> 3);
    const int m0 = tm * 128;
    const int b = m0 >> 12;
    const int slice = (m0 & (N_ - 1)) >> 7;      // 0..31

    const long ldaB = (long)KDIM * 2;
    const int srA = w * 8 + (l >> 3);
    const int kbs = (l & 7) * 16;
    const int kbx = kbs ^ ((srA & 7) << 4);
    long offA[2];
    offA[0] = (long)(srA) * ldaB + kbx;
    offA[1] = (long)(64 + srA) * ldaB + kbx;

    const char* Abase = (const char*)(xb + (size_t)m0 * KDIM);
    const char* Vbase = (const char*)Vmat + (PATH ? (size_t)b * 16 * KDIM * 2 : 0);

    const int kx0 = (g * 16) ^ ((lr & 7) << 4);
    const int kx1 = (64 + g * 16) ^ ((lr & 7) << 4);

#define STG_A(buf_, kt_) { \
    const char* s0_ = Abase + (long)(kt_) * 2; \
    char* d0_ = smem + (buf_) * 16384 + w * 1024; \
    gload16(s0_ + offA[0], d0_); \
    gload16(s0_ + offA[1], d0_ + 8192); }

    if (w < 2) {
        const int rw = l >> 3;
        const int by = ((l & 7) * 16) ^ (rw << 4);
#pragma unroll
        for (int k6 = 0; k6 < 6; ++k6) {
            const int kt = w * 6 + k6;
            gload16(Vbase + (size_t)rw * 1536 + kt * 128 + by,
                    smem + 32768 + kt * 2048);
            gload16(Vbase + (size_t)(8 + rw) * 1536 + kt * 128 + by,
                    smem + 32768 + kt * 2048 + 1024);
        }
    }
    STG_A(0, 0); STG_A(1, 64);
    VM2(); BARX();

    // phase 1: scores = x @ V^T  (wave w owns rows w*16..+15)
    f4v sacc = {};
    const int hi1 = w >> 2, loc1 = (w & 3) * 16;
    for (int kt = 0; kt < 12; ++kt) {
        const int buf = kt & 1;
        {
            const char* ab = smem + buf * 16384 + hi1 * 8192 + (loc1 + lr) * 128;
            s8v a0 = *(const s8v*)(ab + kx0);
            s8v a1 = *(const s8v*)(ab + kx1);
            const char* vb = smem + 32768 + kt * 2048 + lr * 128;
            s8v b0 = *(const s8v*)(vb + kx0);
            s8v b1 = *(const s8v*)(vb + kx1);
            sacc = __builtin_amdgcn_mfma_f32_16x16x32_bf16(a0, b0, sacc, 0, 0, 0);
            sacc = __builtin_amdgcn_mfma_f32_16x16x32_bf16(a1, b1, sacc, 0, 0, 0);
        }
        BARX();
        if (kt + 2 < 12) STG_A(buf, (kt + 2) * 64);
        if (kt <= 9) { VM2(); } else { VM0(); }
        BARX();
    }

    float dd[4];
#pragma unroll
    for (int r = 0; r < 4; ++r) dd[r] = sacc[r] * SCALE_;

    float mw = fmaxf(fmaxf(dd[0], dd[1]), fmaxf(dd[2], dd[3]));
    mw = fmaxf(mw, __shfl_xor(mw, 16));
    mw = fmaxf(mw, __shfl_xor(mw, 32));
    float* Lm = (float*)(smem + LMOFF);
    float* Ls = (float*)(smem + LSOFF);
    if (l < 16) Lm[w * 16 + lr] = mw;
    __syncthreads();
    float mfin = Lm[lr];
#pragma unroll
    for (int w2 = 1; w2 < 8; ++w2) mfin = fmaxf(mfin, Lm[w2 * 16 + lr]);

    float ss = 0.f;
#pragma unroll
    for (int r = 0; r < 4; ++r) {
        const float e = __expf(dd[r] - mfin);
        ss += e;
        const int row = w * 16 + g * 4 + r;
        *(unsigned short*)(smem + EOFF + lr * 352 + row * 2) = f2bf(e);
    }
    ss += __shfl_xor(ss, 16);
    ss += __shfl_xor(ss, 32);
    if (l < 16) Ls[w * 16 + lr] = ss;
    __syncthreads();

    if (tid < 12) {
        float S = 0.f;
#pragma unroll
        for (int w2 = 0; w2 < 8; ++w2) S += Ls[w2 * 16 + tid];
        float M2 = Lm[tid];
#pragma unroll
        for (int w2 = 1; w2 < 8; ++w2) M2 = fmaxf(M2, Lm[w2 * 16 + tid]);
        pms[((size_t)(b * H_ + tid) * 32 + slice) * 2 + 0] = M2;
        pms[((size_t)(b * H_ + tid) * 32 + slice) * 2 + 1] = S;
    }
    __syncthreads();

    // phase 2: P[h][d] = sum_n E[n][h] x[n][d]
    for (int it = 0; it < 6; ++it) {
        STG_A(0, (it * 2) * 64);
        STG_A(1, (it * 2 + 1) * 64);
        VM0(); BARX();
        const int buf = w >> 2;
        const int kt = it * 2 + buf;
        const int d0 = (w & 3) * 16;
        const int dby = (d0 + (l & 15)) * 2;
        f4v pacc = {};
#pragma unroll
        for (int c = 0; c < 4; ++c) {
            s8v ae = *(const s8v*)(smem + EOFF + (l & 15) * 352
                                   + (c * 32 + (l >> 4) * 8) * 2);
            const char* xr = smem + buf * 16384 + (c >> 1) * 8192;
            const int nb = (c & 1) * 32 + (l >> 4) * 8;
            s8v bx;
#pragma unroll
            for (int j = 0; j < 8; ++j)
                bx[j] = (short)*(const unsigned short*)(xr + (nb + j) * 128 + (dby ^ (j << 4)));
            pacc = __builtin_amdgcn_mfma_f32_16x16x32_bf16(ae, bx, pacc, 0, 0, 0);
        }
        if ((l >> 4) < 3) {
#pragma unroll
            for (int r = 0; r < 4; ++r) {
                const int h = (l >> 4) * 4 + r;
                pv[((size_t)(b * 32 + slice) * 12 + h) * 768
                   + kt * 64 + d0 + (l & 15)] = pacc[r];
            }
        }
        BARX();
    }
#undef STG_A
}

// ---------------- 128x256 4-phase bf16 GEMM (unchanged, proven) ----------------
template<int MODE>
__global__ __launch_bounds__(512, 2)
void gemm128(const unsigned short* __restrict__ A, int ldaE,
             const unsigned short* __restrict__ Bmat,
             float* __restrict__ Cf, unsigned short* __restrict__ CbO,
             const float* __restrict__ bias, const float* __restrict__ addW,
             int Nc, int ntn)
{
    __shared__ __align__(16) char smem[98304];
    const int tid = threadIdx.x;
    const int l = tid & 63, w = tid >> 6;
    const int lr = l & 15, g = l >> 4;
    const int wm = w >> 2, wn = w & 3;

    const int nwg = gridDim.x, cpx = nwg >> 3;
    const int bid = blockIdx.x;
    const int lg = (bid & 7) * cpx + (bid >> 3);
    const int tm = lg / ntn, tn = lg % ntn;
    const int m0 = tm * 128, n0 = tn * 256;

    const long ldaB = (long)ldaE * 2;
    const long ldbB = (long)KDIM * 2;

    const unsigned short* Bp = Bmat;
    if (MODE == 0) Bp = Bmat + (size_t)(m0 >> 12) * (DIM_ * DIM_);

    const int srA = w * 8 + (l >> 3);
    const int kbs = (l & 7) * 16;
    const int kbx = kbs ^ ((srA & 7) << 4);
    long offA[2], offB[2];
    offA[0] = (long)(srA) * ldaB + kbx;
    offA[1] = (long)(64 + srA) * ldaB + kbx;
    offB[0] = (long)(((srA >> 5)) * 64 + (srA & 31)) * ldbB + kbx;
    offB[1] = (long)((2 + (srA >> 5)) * 64 + (srA & 31)) * ldbB + kbx;

    const char* Abase = (const char*)(A + (size_t)m0 * ldaE);
    const char* Bbase = (const char*)(Bp + (size_t)n0 * KDIM);

    const int aoff = (wm * 64 + lr) * 128;
    const int boff = (wn * 32 + lr) * 128;
    const int kx0 = (g * 16) ^ ((lr & 7) << 4);
    const int kx1 = (64 + g * 16) ^ ((lr & 7) << 4);

    f4v acc[4][4] = {};
    s8v af[4][2];
    s8v bfr[2][2][2];

#define STG_A1(buf_, kt_) { \
    const char* s0_ = Abase + (long)(kt_) * 2; \
    char* d0_ = smem + ((buf_) * 3) * 16384 + w * 1024; \
    gload16(s0_ + offA[0], d0_); \
    gload16(s0_ + offA[1], d0_ + 8192); }

#define STG_B1(buf_, qn_, kt_) { \
    const char* s0_ = Bbase + (long)(kt_) * 2 + (long)(qn_) * 32 * ldbB; \
    char* d0_ = smem + ((buf_) * 3 + 1 + (qn_)) * 16384 + w * 1024; \
    gload16(s0_ + offB[0], d0_); \
    gload16(s0_ + offB[1], d0_ + 8192); }

#define DS_A1(buf_) { \
    const char* ba_ = smem + ((buf_) * 3) * 16384 + aoff; \
    af[0][0] = *(const s8v*)(ba_ +    0 + kx0); af[0][1] = *(const s8v*)(ba_ +    0 + kx1); \
    af[1][0] = *(const s8v*)(ba_ + 2048 + kx0); af[1][1] = *(const s8v*)(ba_ + 2048 + kx1); \
    af[2][0] = *(const s8v*)(ba_ + 4096 + kx0); af[2][1] = *(const s8v*)(ba_ + 4096 + kx1); \
    af[3][0] = *(const s8v*)(ba_ + 6144 + kx0); af[3][1] = *(const s8v*)(ba_ + 6144 + kx1); }

#define DS_B1(buf_, qn_) { \
    const char* bb_ = smem + ((buf_) * 3 + 1 + (qn_)) * 16384 + boff; \
    bfr[qn_][0][0] = *(const s8v*)(bb_ +    0 + kx0); bfr[qn_][0][1] = *(const s8v*)(bb_ +    0 + kx1); \
    bfr[qn_][1][0] = *(const s8v*)(bb_ + 2048 + kx0); bfr[qn_][1][1] = *(const s8v*)(bb_ + 2048 + kx1); }

#define MM1(fm_, fng_, qn_, kk_) \
    acc[fm_][fng_] = __builtin_amdgcn_mfma_f32_16x16x32_bf16(af[fm_][kk_], bfr[qn_][(fng_)&1][kk_], acc[fm_][fng_], 0, 0, 0);

#define MFMA16_1(qn_, kk_) \
    MM1(0, (qn_)*2+0, qn_, kk_) MM1(0, (qn_)*2+1, qn_, kk_) \
    MM1(1, (qn_)*2+0, qn_, kk_) MM1(1, (qn_)*2+1, qn_, kk_) \
    MM1(2, (qn_)*2+0, qn_, kk_) MM1(2, (qn_)*2+1, qn_, kk_) \
    MM1(3, (qn_)*2+0, qn_, kk_) MM1(3, (qn_)*2+1, qn_, kk_)

#define MFMA32_1(qn_) { MFMA16_1(qn_, 0) MFMA16_1(qn_, 1) }

    STG_A1(0, 0); STG_B1(0, 0, 0); STG_B1(0, 1, 0);
    STG_A1(1, 64); STG_B1(1, 0, 64);
    VM4(); BARX();

    for (int i = 0; i < NITER; ++i) {
        const int t1k = (2 * i + 1) * 64, t2k = (2 * i + 2) * 64, t3k = (2 * i + 3) * 64;
        const bool h2 = (2 * i + 2) < NKT, h3 = (2 * i + 3) < NKT;
        const bool last = (i == NITER - 1);
        DS_A1(0); DS_B1(0, 0); STG_B1(1, 1, t1k);
        BARX(); PRIO1(); MFMA32_1(0); PRIO0(); BARX();
        DS_B1(0, 1); if (h2) { STG_A1(0, t2k); STG_B1(0, 0, t2k); }
        BARX(); PRIO1(); MFMA32_1(1); PRIO0();
        if (last) { VM0(); } else { VM4(); }
        BARX();
        DS_A1(1); DS_B1(1, 0); if (h2) STG_B1(0, 1, t2k);
        BARX(); PRIO1(); MFMA32_1(0); PRIO0(); BARX();
        DS_B1(1, 1); if (h3) { STG_A1(1, t3k); STG_B1(1, 0, t3k); }
        BARX(); PRIO1(); MFMA32_1(1); PRIO0();
        if (last) { VM0(); } else { VM4(); }
        BARX();
    }

    const int jb = m0 % DIM_;   // row offset within batch (MODE 1)
#pragma unroll
    for (int fm = 0; fm < 4; ++fm) {
#pragma unroll
        for (int fng = 0; fng < 4; ++fng) {
            const int col = n0 + wn * 64 + fng * 16 + lr;
#pragma unroll
            for (int r = 0; r < 4; ++r) {
                const int ro = wm * 64 + fm * 16 + g * 4 + r;
                const int row = m0 + ro;
                if (MODE == 0) {
                    Cf[(size_t)row * Nc + col] = acc[fm][fng][r] + bias[col];
                } else {
                    CbO[(size_t)row * Nc + col] =
                        f2bf(acc[fm][fng][r] + addW[(size_t)(jb + ro) * DIM_ + col]);
                }
            }
        }
    }
#undef STG_A1
#undef STG_B1
#undef DS_A1
#undef DS_B1
#undef MM1
#undef MFMA16_1
#undef MFMA32_1
}

// ---------------- reduce_a: alpha partials -> bvecs = Wk_h^T(gq*wk)  (bf16) ----------
__global__ __launch_bounds__(256)
void reduce_a(const float* __restrict__ pv1, const float* __restrict__ pms1,
              const float* __restrict__ Wqkv, const float* __restrict__ w_k,
              unsigned short* __restrict__ bvecs)
{
    const int b = blockIdx.x / H_, h = blockIdx.x % H_;
    const int t = threadIdx.x;
    const int w = t >> 6, l = t & 63;
    __shared__ float Svec[768];
    __shared__ float ew[32];
    __shared__ float Ssh;
    __shared__ float gqwk[64];

    const float* pp = pms1 + (size_t)(b * H_ + h) * 32 * 2;
    float M = pp[0];
    for (int s = 1; s < 32; ++s) M = fmaxf(M, pp[s * 2]);
    if (t < 32) ew[t] = __expf(pp[t * 2] - M);
    __syncthreads();
    if (t == 0) {
        float S = 0.f;
        for (int s = 0; s < 32; ++s) S += ew[s] * pp[s * 2 + 1];
        Ssh = S;
    }
#pragma unroll
    for (int j = 0; j < 3; ++j) {
        const int col = t + j * 256;
        float v = 0.f;
        for (int s = 0; s < 32; ++s)
            v += ew[s] * pv1[((size_t)(b * 32 + s) * 12 + h) * 768 + col];
        Svec[col] = v;
    }
    __syncthreads();

    const float invS = 1.f / Ssh;
    for (int i = 0; i < 16; ++i) {
        const int o = w * 16 + i;
        const float* wr = Wqkv + (size_t)(h * 64 + o) * 768;
        float s = 0.f;
#pragma unroll
        for (int j = 0; j < 12; ++j)
            s += wr[l + j * 64] * Svec[l + j * 64];
        s += __shfl_xor(s, 1); s += __shfl_xor(s, 2); s += __shfl_xor(s, 4);
        s += __shfl_xor(s, 8); s += __shfl_xor(s, 16); s += __shfl_xor(s, 32);
        if (l == 0) gqwk[o] = (s * invS) * w_k[h * 64 + o];
    }
    __syncthreads();

#pragma unroll
    for (int j = 0; j < 3; ++j) {
        const int dcol = t + j * 256;
        float bv = 0.f;
        for (int c = 0; c < 64; ++c)
            bv += gqwk[c] * Wqkv[(size_t)(DIM_ + h * 64 + c) * 768 + dcol];
        bvecs[(size_t)(b * 16 + h) * 768 + dcol] = f2bf(bv);
        if (h < 4) bvecs[(size_t)(b * 16 + 12 + h) * 768 + dcol] = 0;
    }
}

// ---------------- reduce_b: beta partials -> gkv[b*768 + h*64 + o] ----------
__global__ __launch_bounds__(256)
void reduce_b(const float* __restrict__ pv2, const float* __restrict__ pms2,
              const float* __restrict__ Wqkv, float* __restrict__ gkv)
{
    const int b = blockIdx.x / H_, h = blockIdx.x % H_;
    const int t = threadIdx.x;
    const int w = t >> 6, l = t & 63;
    __shared__ float Svec[768];
    __shared__ float ew[32];
    __shared__ float Ssh;

    const float* pp = pms2 + (size_t)(b * H_ + h) * 32 * 2;
    float M = pp[0];
    for (int s = 1; s < 32; ++s) M = fmaxf(M, pp[s * 2]);
    if (t < 32) ew[t] = __expf(pp[t * 2] - M);
    __syncthreads();
    if (t == 0) {
        float S = 0.f;
        for (int s = 0; s < 32; ++s) S += ew[s] * pp[s * 2 + 1];
        Ssh = S;
    }
#pragma unroll
    for (int j = 0; j < 3; ++j) {
        const int col = t + j * 256;
        float v = 0.f;
        for (int s = 0; s < 32; ++s)
            v += ew[s] * pv2[((size_t)(b * 32 + s) * 12 + h) * 768 + col];
        Svec[col] = v;
    }
    __syncthreads();

    const float invS = 1.f / Ssh;
    for (int i = 0; i < 16; ++i) {
        const int o = w * 16 + i;
        const float* wr = Wqkv + (size_t)(DIM_ + h * 64 + o) * 768;
        float s = 0.f;
#pragma unroll
        for (int j = 0; j < 12; ++j)
            s += wr[l + j * 64] * Svec[l + j * 64];
        s += __shfl_xor(s, 1); s += __shfl_xor(s, 2); s += __shfl_xor(s, 4);
        s += __shfl_xor(s, 8); s += __shfl_xor(s, 16); s += __shfl_xor(s, 32);
        if (l == 0) gkv[(size_t)b * DIM_ + h * 64 + o] = s * invS;
    }
}

// ---------------- conversion (grid-stride) + fused avec_prep ----------
// Blocks [0,16): avec rows (fast, scheduled first).  Blocks [16, 16+NCVT): grid-stride
// over n4tot float4 items (x cvt then wvT transpose).
__global__ void cvt_all(const float* __restrict__ x, const float* __restrict__ Wqkv,
                        const float* __restrict__ w_q,
                        unsigned short* __restrict__ xb, unsigned short* __restrict__ wvT,
                        unsigned short* __restrict__ avecb,
                        int n4x, int n4tot)
{
    if ((int)blockIdx.x < 16) {
        const int h = blockIdx.x;
        const int t = threadIdx.x;
        if (h >= H_) {
#pragma unroll
            for (int j = 0; j < 3; ++j) avecb[(size_t)h * 768 + t + j * 256] = 0;
            return;
        }
        __shared__ float wl[64];
        if (t < 64) wl[t] = w_q[h * 64 + t];
        __syncthreads();
#pragma unroll
        for (int j = 0; j < 3; ++j) {
            const int dcol = t + j * 256;
            float a = 0.f;
            for (int c = 0; c < 64; ++c)
                a += wl[c] * Wqkv[(size_t)(h * 64 + c) * 768 + dcol];
            avecb[(size_t)h * 768 + dcol] = f2bf(a);
        }
        return;
    }
    const int nb = gridDim.x - 16;
    const int stride = nb * 256;
    for (int i = (blockIdx.x - 16) * 256 + threadIdx.x; i < n4tot; i += stride) {
        if (i < n4x) {
            float4 v = ((const float4*)x)[i];
            ushort4 o;
            o.x = f2bf(v.x); o.y = f2bf(v.y); o.z = f2bf(v.z); o.w = f2bf(v.w);
            ((ushort4*)xb)[i] = o;
        } else {
            const int k = i - n4x;
            const int ii = k % DIM_;
            const int c0 = (k / DIM_) * 4;
            ushort4 o;
            o.x = f2bf(Wqkv[(size_t)(2 * DIM_ + c0 + 0) * DIM_ + ii]);
            o.y = f2bf(Wqkv[(size_t)(2 * DIM_ + c0 + 1) * DIM_ + ii]);
            o.z = f2bf(Wqkv[(size_t)(2 * DIM_ + c0 + 2) * DIM_ + ii]);
            o.w = f2bf(Wqkv[(size_t)(2 * DIM_ + c0 + 3) * DIM_ + ii]);
            *(ushort4*)&wvT[(size_t)ii * DIM_ + c0] = o;
        }
    }
}

// ---------------- fold gk into Wp: W2[b][j][c] = bf16(Wp[j][c] * gk[b*768+c]) --------
__global__ __launch_bounds__(256)
void fold_wp(const float* __restrict__ Wp, const float* __restrict__ gk,
             unsigned short* __restrict__ W2)
{
    int idx = blockIdx.x * 256 + threadIdx.x;
    int e4 = idx * 4;
    int b = (int)((unsigned)e4 / (unsigned)(DIM_ * DIM_));
    int rem = e4 - b * (DIM_ * DIM_);
    int c = rem % DIM_;
    float4 wv = *(const float4*)&Wp[rem];
    const float* gp = &gk[b * DIM_ + c];
    ushort4 o;
    o.x = f2bf(wv.x * gp[0]); o.y = f2bf(wv.y * gp[1]);
    o.z = f2bf(wv.z * gp[2]); o.w = f2bf(wv.w * gp[3]);
    *(ushort4*)&W2[e4] = o;
}

extern "C" void kernel_launch(void* const* d_in, const int* in_sizes, int n_in,
                              void* d_out, int out_size, void* d_ws, size_t ws_size,
                              hipStream_t stream)
{
    const float* x    = (const float*)d_in[0];
    const float* Wqkv = (const float*)d_in[1];
    const float* Wp   = (const float*)d_in[2];
    const float* bp   = (const float*)d_in[3];
    const float* w_q  = (const float*)d_in[4];
    const float* w_k  = (const float*)d_in[5];
    float* out = (float*)d_out;

    constexpr size_t NXB = (size_t)M_ * DIM_;
    constexpr size_t NWV = (size_t)DIM_ * DIM_;
    constexpr size_t NW2 = (size_t)B_ * DIM_ * DIM_;

    char* p = (char*)d_ws;
    unsigned short* xb    = (unsigned short*)p; p += NXB * 2;
    unsigned short* wvT   = (unsigned short*)p; p += NWV * 2;
    unsigned short* w2b   = (unsigned short*)p; p += NW2 * 2;
    unsigned short* w4b   = (unsigned short*)p; p += NW2 * 2;
    unsigned short* avecb = (unsigned short*)p; p += (size_t)16 * 768 * 2;
    unsigned short* bvecs = (unsigned short*)p; p += (size_t)B_ * 16 * 768 * 2;
    float* pv1  = (float*)p; p += (size_t)B_ * 32 * 12 * 768 * 4;
    float* pms1 = (float*)p; p += (size_t)B_ * H_ * 32 * 2 * 4;
    float* pv2  = (float*)p; p += (size_t)B_ * 32 * 12 * 768 * 4;
    float* pms2 = (float*)p; p += (size_t)B_ * H_ * 32 * 2 * 4;
    float* gkv  = (float*)p; p += (size_t)B_ * DIM_ * 4;

    // 1) convert x (bf16) + Wv^T (bf16) + avec; grid-stride at 2048 blocks + 16 avec
    constexpr int N4X  = (int)(NXB / 4);
    constexpr int N4T  = N4X + (int)(NWV / 4);
    cvt_all<<<2048 + 16, 256, 0, stream>>>(x, Wqkv, w_q, xb, wvT, avecb, N4X, N4T);

    // 2) alpha score pass (256 blocks, 2/CU)
    score_pass<0><<<256, 512, 0, stream>>>(xb, avecb, pv1, pms1);

    // 3) alpha reduce -> bvecs = Wk_h^T(gq*wk)  (bf16 [B][16][768])
    reduce_a<<<B_ * H_, 256, 0, stream>>>(pv1, pms1, Wqkv, w_k, bvecs);

    // 4) beta score pass (256 blocks)
    score_pass<1><<<256, 512, 0, stream>>>(xb, bvecs, pv2, pms2);

    // 5) beta reduce -> gkv = global_k
    reduce_b<<<B_ * H_, 256, 0, stream>>>(pv2, pms2, Wqkv, gkv);

    // 6) W2[b] = Wp * gk_b (bf16)
    fold_wp<<<(int)(NW2 / 4 / 256), 256, 0, stream>>>(Wp, gkv, w2b);

    // 7) W4 = W2 @ Wv + Wq  (flat [6144,768] GEMM, 144 blocks)
    gemm128<1><<<48 * 3, 512, 0, stream>>>(w2b, DIM_, wvT, nullptr, w4b, nullptr, Wqkv,
                                           DIM_, 3);

    // 8) out = x @ W4_b^T + bp   (768 blocks)
    gemm128<0><<<256 * 3, 512, 0, stream>>>(xb, DIM_, w4b, out, nullptr, bp, nullptr,
                                            DIM_, 3);
}